// Round 5
// baseline (89.983 us; speedup 1.0000x reference)
//
#include <hip/hip_runtime.h>
#include <hip/hip_bf16.h>
#include <math.h>

#define BATCH 8
#define LSEQ 2048
#define DM 128
#define NH 4
#define DK 32

constexpr float SCALE = 0.17677669529663687f;   // 1/sqrt(32)
constexpr float LOG2E = 1.4426950408889634f;
constexpr float SL = SCALE * LOG2E;             // folded into Q at qkv store

typedef __attribute__((ext_vector_type(8))) __bf16 bf16x8;
typedef __attribute__((ext_vector_type(16))) float f32x16;

__device__ __forceinline__ bf16x8 as_bf16x8(uint4 u) {
    union { uint4 a; bf16x8 b; } c; c.a = u; return c.b;
}
__device__ __forceinline__ unsigned pack_bf2(float lo, float hi) {
    __hip_bfloat162 h = __float22bfloat162_rn(make_float2(lo, hi));
    union { __hip_bfloat162 a; unsigned b; } c; c.a = h; return c.b;
}

// ---------- kernel 0: per-batch exclusive scan of unmasked keys ----------
__global__ __launch_bounds__(256) void scan_kernel(const float* __restrict__ mask,
                                                   int* __restrict__ cpos,
                                                   int* __restrict__ cnt)
{
    const int b = blockIdx.x;
    const int tid = threadIdx.x;
    __shared__ int ps[256];
    const float* mb = mask + (size_t)b * LSEQ;
    const int base = tid * 8;
    int loc[8];
    int sum = 0;
    #pragma unroll
    for (int i = 0; i < 8; ++i) {
        int u = (mb[base + i] == 0.0f) ? 1 : 0;
        loc[i] = sum;
        sum += u;
    }
    ps[tid] = sum;
    __syncthreads();
    for (int off = 1; off < 256; off <<= 1) {
        int v = (tid >= off) ? ps[tid - off] : 0;
        __syncthreads();
        ps[tid] += v;
        __syncthreads();
    }
    const int prev = (tid > 0) ? ps[tid - 1] : 0;
    #pragma unroll
    for (int i = 0; i < 8; ++i)
        cpos[(size_t)b * LSEQ + base + i] = prev + loc[i];
    if (tid == 255) cnt[b] = ps[255];
}

// ---------- kernel 1: QKV projection via MFMA ----------
// Q is pre-scaled by SCALE*LOG2E so attn can exp2 scores directly.
__global__ __launch_bounds__(256) void qkv_mfma_kernel(const float* __restrict__ x,
    const float* __restrict__ Wq, const float* __restrict__ Wk, const float* __restrict__ Wv,
    const float* __restrict__ mask, const int* __restrict__ cpos,
    unsigned short* __restrict__ Qb, unsigned short* __restrict__ Kb,
    unsigned short* __restrict__ Vcb)
{
    const int b = blockIdx.x;                 // 8
    const int which = blockIdx.y;             // 0=Q 1=K 2=V
    const int lt = blockIdx.z;                // 32 tiles of 64 l
    const int tid = threadIdx.x;
    const int wv = tid >> 6;                  // 4 waves
    const int lane = tid & 63;
    const int ql = lane & 31;
    const int hi = lane >> 5;
    const int l = lt * 64 + (wv & 1) * 32 + ql;   // this lane's output row
    const int hbase = (wv >> 1) * 2;              // head pair

    const float* W = (which == 0 ? Wq : (which == 1 ? Wk : Wv));
    const float* xcol = x + (size_t)b * DM * LSEQ + l;   // x[b][d][l]

    f32x16 acc0, acc1;
    #pragma unroll
    for (int r = 0; r < 16; ++r) { acc0[r] = 0.f; acc1[r] = 0.f; }

    #pragma unroll
    for (int d0 = 0; d0 < DM; d0 += 16) {
        const int dbase = d0 + 8 * hi;
        float xv[8];
        #pragma unroll
        for (int i = 0; i < 8; ++i) xv[i] = xcol[(size_t)(dbase + i) * LSEQ];
        uint4 xp = make_uint4(pack_bf2(xv[0], xv[1]), pack_bf2(xv[2], xv[3]),
                              pack_bf2(xv[4], xv[5]), pack_bf2(xv[6], xv[7]));
        const bf16x8 xf = as_bf16x8(xp);
        const float* wr0 = W + ((size_t)(hbase + 0) * DM + dbase) * DK + ql;
        const float* wr1 = W + ((size_t)(hbase + 1) * DM + dbase) * DK + ql;
        float w0[8], w1[8];
        #pragma unroll
        for (int i = 0; i < 8; ++i) { w0[i] = wr0[i * DK]; w1[i] = wr1[i * DK]; }
        uint4 wp0 = make_uint4(pack_bf2(w0[0], w0[1]), pack_bf2(w0[2], w0[3]),
                               pack_bf2(w0[4], w0[5]), pack_bf2(w0[6], w0[7]));
        uint4 wp1 = make_uint4(pack_bf2(w1[0], w1[1]), pack_bf2(w1[2], w1[3]),
                               pack_bf2(w1[4], w1[5]), pack_bf2(w1[6], w1[7]));
        acc0 = __builtin_amdgcn_mfma_f32_32x32x16_bf16(as_bf16x8(wp0), xf, acc0, 0, 0, 0);
        acc1 = __builtin_amdgcn_mfma_f32_32x32x16_bf16(as_bf16x8(wp1), xf, acc1, 0, 0, 0);
    }

    bool store = true;
    int slot = l;
    if (which != 0) {
        if (mask[(size_t)b * LSEQ + l] == 0.0f) slot = cpos[(size_t)b * LSEQ + l];
        else store = false;
    }
    if (store) {
        const float fold = (which == 0) ? SL : 1.0f;
        unsigned short* base0 = (which == 0 ? Qb : (which == 1 ? Kb : Vcb));
        #pragma unroll
        for (int hh = 0; hh < 2; ++hh) {
            const f32x16& A = hh ? acc1 : acc0;
            const int bh = b * NH + hbase + hh;
            unsigned short* rowp = base0 + ((size_t)bh * LSEQ + slot) * DK;
            unsigned dw[8];
            #pragma unroll
            for (int j = 0; j < 8; ++j) dw[j] = pack_bf2(A[2*j] * fold, A[2*j+1] * fold);
            *reinterpret_cast<uint2*>(rowp + 4*hi)      = make_uint2(dw[0], dw[1]);
            *reinterpret_cast<uint2*>(rowp + 8 + 4*hi)  = make_uint2(dw[2], dw[3]);
            *reinterpret_cast<uint2*>(rowp + 16 + 4*hi) = make_uint2(dw[4], dw[5]);
            *reinterpret_cast<uint2*>(rowp + 24 + 4*hi) = make_uint2(dw[6], dw[7]);
        }
    }
}

// ---------- kernel 1b: transpose Vcb[slot][32] -> Vt[d][slot] (bf16) ----------
__global__ __launch_bounds__(256) void vtrans_kernel(const unsigned short* __restrict__ Vcb,
                                                     unsigned short* __restrict__ Vt)
{
    const int bh = blockIdx.y;
    const int s0 = blockIdx.x * 256;
    __shared__ unsigned lds[256][17];
    const int t = threadIdx.x;
    const uint4* src = reinterpret_cast<const uint4*>(Vcb + ((size_t)bh * LSEQ + s0 + t) * DK);
    uint4 r0 = src[0], r1 = src[1], r2 = src[2], r3 = src[3];
    unsigned* lr = lds[t];
    lr[0]=r0.x;  lr[1]=r0.y;  lr[2]=r0.z;  lr[3]=r0.w;
    lr[4]=r1.x;  lr[5]=r1.y;  lr[6]=r1.z;  lr[7]=r1.w;
    lr[8]=r2.x;  lr[9]=r2.y;  lr[10]=r2.z; lr[11]=r2.w;
    lr[12]=r3.x; lr[13]=r3.y; lr[14]=r3.z; lr[15]=r3.w;
    __syncthreads();
    const int d = t & 31;
    const int c = (t >> 5) * 32;
    const int dw = d >> 1;
    const int dh = (d & 1) * 16;
    unsigned ow[16];
    #pragma unroll
    for (int i = 0; i < 16; ++i) {
        unsigned lo = (lds[c + 2*i][dw] >> dh) & 0xffffu;
        unsigned hv = (lds[c + 2*i + 1][dw] >> dh) & 0xffffu;
        ow[i] = lo | (hv << 16);
    }
    uint4* dstp = reinterpret_cast<uint4*>(Vt + ((size_t)bh * DK + d) * LSEQ + s0 + c);
    dstp[0] = make_uint4(ow[0],  ow[1],  ow[2],  ow[3]);
    dstp[1] = make_uint4(ow[4],  ow[5],  ow[6],  ow[7]);
    dstp[2] = make_uint4(ow[8],  ow[9],  ow[10], ow[11]);
    dstp[3] = make_uint4(ow[12], ow[13], ow[14], ow[15]);
}

// ---------- kernel 2: MFMA flash attention, 4-way key split, bf16 Hd out ----------
__global__ __launch_bounds__(256, 8) void attn_kernel(
    const unsigned short* __restrict__ Qb, const unsigned short* __restrict__ Kb,
    const unsigned short* __restrict__ Vt, const float* __restrict__ mask,
    const int* __restrict__ cnt, unsigned short* __restrict__ Hd)
{
    const int bh = blockIdx.y;
    const int b = bh >> 2;
    const int h = bh & 3;
    const int lane = threadIdx.x & 63;
    const int kw = threadIdx.x >> 6;              // key-quarter owner (0..3)
    const int ql = lane & 31;
    const int hi = lane >> 5;
    const int q0 = blockIdx.x * 32;
    const int n = cnt[b];

    const uint4* Qp = reinterpret_cast<const uint4*>(Qb + ((size_t)bh * LSEQ + q0 + ql) * DK);
    const bf16x8 qf0 = as_bf16x8(Qp[hi]);         // Q[q=ql][d=8*hi+i] (pre-scaled)
    const bf16x8 qf1 = as_bf16x8(Qp[2 + hi]);     // d = 16+8*hi+i

    const unsigned short* Kbase = Kb + (size_t)bh * LSEQ * DK;
    const unsigned short* Vbase = Vt + ((size_t)bh * DK + ql) * LSEQ;

    f32x16 acc;
    #pragma unroll
    for (int r = 0; r < 16; ++r) acc[r] = 0.f;
    f32x16 zero;
    #pragma unroll
    for (int r = 0; r < 16; ++r) zero[r] = 0.f;
    float lacc = 0.f;

    auto tile = [&](int k0, bool pred) {
        const uint4* Kp = reinterpret_cast<const uint4*>(Kbase + (size_t)(k0 + ql) * DK);
        bf16x8 kf0 = as_bf16x8(Kp[hi]);           // K[key=ql][d=8*hi+i]
        bf16x8 kf1 = as_bf16x8(Kp[2 + hi]);
        f32x16 s = __builtin_amdgcn_mfma_f32_32x32x16_bf16(kf0, qf0, zero, 0, 0, 0);
        s = __builtin_amdgcn_mfma_f32_32x32x16_bf16(kf1, qf1, s, 0, 0, 0);
        const uint4* Vp = reinterpret_cast<const uint4*>(Vbase + k0);
        bf16x8 vf0 = as_bf16x8(Vp[hi]);           // Vt[d=ql][k0+8*hi+i]
        bf16x8 vf1 = as_bf16x8(Vp[2 + hi]);       // keys k0+16..k0+31
        unsigned w[8], sw[8];
        #pragma unroll
        for (int j = 0; j < 8; ++j) {
            float e0 = exp2f(s[2*j]);             // key = k0+(r&3)+8*(r>>2)+4*hi
            float e1 = exp2f(s[2*j+1]);
            if (pred) {
                const int r0 = 2*j, r1 = 2*j + 1;
                if (k0 + (r0 & 3) + 8*(r0 >> 2) + 4*hi >= n) e0 = 0.f;
                if (k0 + (r1 & 3) + 8*(r1 >> 2) + 4*hi >= n) e1 = 0.f;
            }
            lacc += e0 + e1;
            w[j] = pack_bf2(e0, e1);
        }
        #pragma unroll
        for (int j = 0; j < 8; ++j) sw[j] = __shfl_xor(w[j], 32);
        uint4 b0 = hi ? make_uint4(sw[2], sw[3], w[2], w[3])
                      : make_uint4(w[0], w[1], sw[0], sw[1]);
        uint4 b1 = hi ? make_uint4(sw[6], sw[7], w[6], w[7])
                      : make_uint4(w[4], w[5], sw[4], sw[5]);
        acc = __builtin_amdgcn_mfma_f32_32x32x16_bf16(vf0, as_bf16x8(b0), acc, 0, 0, 0);
        acc = __builtin_amdgcn_mfma_f32_32x32x16_bf16(vf1, as_bf16x8(b1), acc, 0, 0, 0);
    };

    const int nfull = n & ~31;
    for (int k0 = kw * 32; k0 < nfull; k0 += 128) tile(k0, false);
    if (n & 31) {
        if (((nfull >> 5) & 3) == kw) tile(nfull, true);
    }

    // merge 4 wave-partials (pure sums) via LDS
    __shared__ float red[3][64][17];
    if (kw > 0) {
        #pragma unroll
        for (int r = 0; r < 16; ++r) red[kw - 1][lane][r] = acc[r];
        red[kw - 1][lane][16] = lacc;
    }
    __syncthreads();
    if (kw == 0) {
        #pragma unroll
        for (int c = 0; c < 3; ++c) {
            #pragma unroll
            for (int r = 0; r < 16; ++r) acc[r] += red[c][lane][r];
            lacc += red[c][lane][16];
        }
        const float lf = lacc + __shfl_xor(lacc, 32);
        const float mq = mask[(size_t)b * LSEQ + q0 + ql];
        const float wgt = (lf > 0.f) ? (mq / lf) : 0.f;
        unsigned short* orow = Hd + ((size_t)b * LSEQ + q0 + ql) * DM + h * DK + 4 * hi;
        #pragma unroll
        for (int g = 0; g < 4; ++g) {            // d = 8g + 4hi + (0..3)
            uint2 p = make_uint2(pack_bf2(acc[4*g+0]*wgt, acc[4*g+1]*wgt),
                                 pack_bf2(acc[4*g+2]*wgt, acc[4*g+3]*wgt));
            *reinterpret_cast<uint2*>(orow + 8*g) = p;
        }
    }
}

// ---------- kernel 3: output projection via MFMA + transposed store ----------
// out[b][j][l] = sum_i Hd[b][l][i] * Wo[i][j]; A=Wo cols (lane=j), B=Hd rows (lane=l)
__global__ __launch_bounds__(256) void proj_mfma_kernel(const unsigned short* __restrict__ Hd,
    const float* __restrict__ Wo, float* __restrict__ out)
{
    const int blk = blockIdx.x;                   // 512 = 8 b x 64 l-tiles
    const int b = blk >> 6;
    const int l0 = (blk & 63) * 32;
    const int tid = threadIdx.x;
    const int jt = tid >> 6;                      // j-tile per wave
    const int lane = tid & 63;
    const int ql = lane & 31;
    const int hi = lane >> 5;

    const unsigned short* hrow = Hd + ((size_t)b * LSEQ + l0 + ql) * DM;

    f32x16 acc;
    #pragma unroll
    for (int r = 0; r < 16; ++r) acc[r] = 0.f;

    #pragma unroll
    for (int ks = 0; ks < 8; ++ks) {
        const int k0 = ks * 16 + 8 * hi;
        uint4 bp = *reinterpret_cast<const uint4*>(hrow + k0);      // Hd[l][k0..k0+7]
        const float* wcol = Wo + (size_t)k0 * DM + jt * 32 + ql;    // Wo[k][j]
        float w[8];
        #pragma unroll
        for (int i = 0; i < 8; ++i) w[i] = wcol[(size_t)i * DM];
        uint4 ap = make_uint4(pack_bf2(w[0], w[1]), pack_bf2(w[2], w[3]),
                              pack_bf2(w[4], w[5]), pack_bf2(w[6], w[7]));
        acc = __builtin_amdgcn_mfma_f32_32x32x16_bf16(as_bf16x8(ap), as_bf16x8(bp), acc, 0, 0, 0);
    }

    float* obase = out + (size_t)b * DM * LSEQ + l0 + ql;
    #pragma unroll
    for (int r = 0; r < 16; ++r) {
        const int j = jt * 32 + (r & 3) + 8 * (r >> 2) + 4 * hi;
        obase[(size_t)j * LSEQ] = acc[r];         // coalesced across ql
    }
}

extern "C" void kernel_launch(void* const* d_in, const int* in_sizes, int n_in,
                              void* d_out, int out_size, void* d_ws, size_t ws_size,
                              hipStream_t stream)
{
    const float* x    = (const float*)d_in[0];
    const float* mask = (const float*)d_in[1];
    const float* Wq   = (const float*)d_in[2];
    const float* Wk   = (const float*)d_in[3];
    const float* Wv   = (const float*)d_in[4];
    const float* Wo   = (const float*)d_in[5];
    float* out = (float*)d_out;

    char* wsb = (char*)d_ws;
    const size_t NBF = (size_t)BATCH * NH * LSEQ * DK;      // 2,097,152 elems
    unsigned short* Qb  = (unsigned short*)wsb;             // 4MB
    unsigned short* Kb  = Qb + NBF;                         // 4MB
    unsigned short* Vcb = Kb + NBF;                         // 4MB
    unsigned short* Vt  = Vcb + NBF;                        // 4MB
    unsigned short* Hd  = Vt + NBF;                         // 4MB bf16 (B,L,128)
    int* cpos = (int*)(wsb + 24ull * 1024 * 1024);
    int* cnt  = cpos + (size_t)BATCH * LSEQ;

    scan_kernel<<<dim3(BATCH), dim3(256), 0, stream>>>(mask, cpos, cnt);
    qkv_mfma_kernel<<<dim3(BATCH, 3, LSEQ / 64), dim3(256), 0, stream>>>(
        x, Wq, Wk, Wv, mask, cpos, Qb, Kb, Vcb);
    vtrans_kernel<<<dim3(LSEQ / 256, BATCH * NH), dim3(256), 0, stream>>>(Vcb, Vt);
    attn_kernel<<<dim3(LSEQ / 32, BATCH * NH), dim3(256), 0, stream>>>(
        Qb, Kb, Vt, mask, cnt, Hd);
    proj_mfma_kernel<<<dim3(BATCH * LSEQ / 32), dim3(256), 0, stream>>>(Hd, Wo, out);
}

// Round 6
// 59.662 us; speedup vs baseline: 1.5082x; 1.5082x over previous
//
#include <hip/hip_runtime.h>
#include <hip/hip_bf16.h>
#include <math.h>

#define BATCH 8
#define LSEQ 2048
#define DM 128
#define NH 4
#define DK 32

constexpr float SCALE = 0.17677669529663687f;   // 1/sqrt(32)
constexpr float LOG2E = 1.4426950408889634f;
constexpr float SL = SCALE * LOG2E;             // folded into Q at qkv store

typedef __attribute__((ext_vector_type(8))) __bf16 bf16x8;
typedef __attribute__((ext_vector_type(16))) float f32x16;

__device__ __forceinline__ bf16x8 as_bf16x8(uint4 u) {
    union { uint4 a; bf16x8 b; } c; c.a = u; return c.b;
}
__device__ __forceinline__ unsigned pack_bf2(float lo, float hi) {
    __hip_bfloat162 h = __float22bfloat162_rn(make_float2(lo, hi));
    union { __hip_bfloat162 a; unsigned b; } c; c.a = h; return c.b;
}

// ---------- kernel 0: per-batch exclusive scan of unmasked keys ----------
__global__ __launch_bounds__(256) void scan_kernel(const float* __restrict__ mask,
                                                   int* __restrict__ cpos,
                                                   int* __restrict__ cnt)
{
    const int b = blockIdx.x;
    const int tid = threadIdx.x;
    __shared__ int ps[256];
    const float* mb = mask + (size_t)b * LSEQ;
    const int base = tid * 8;
    int loc[8];
    int sum = 0;
    #pragma unroll
    for (int i = 0; i < 8; ++i) {
        int u = (mb[base + i] == 0.0f) ? 1 : 0;
        loc[i] = sum;
        sum += u;
    }
    ps[tid] = sum;
    __syncthreads();
    for (int off = 1; off < 256; off <<= 1) {
        int v = (tid >= off) ? ps[tid - off] : 0;
        __syncthreads();
        ps[tid] += v;
        __syncthreads();
    }
    const int prev = (tid > 0) ? ps[tid - 1] : 0;
    #pragma unroll
    for (int i = 0; i < 8; ++i)
        cpos[(size_t)b * LSEQ + base + i] = prev + loc[i];
    if (tid == 255) cnt[b] = ps[255];
}

// ---------- kernel 1: QKV projection via MFMA ----------
// Q is pre-scaled by SCALE*LOG2E so attn can exp2 scores directly.
__global__ __launch_bounds__(256) void qkv_mfma_kernel(const float* __restrict__ x,
    const float* __restrict__ Wq, const float* __restrict__ Wk, const float* __restrict__ Wv,
    const float* __restrict__ mask, const int* __restrict__ cpos,
    unsigned short* __restrict__ Qb, unsigned short* __restrict__ Kb,
    unsigned short* __restrict__ Vcb)
{
    const int b = blockIdx.x;                 // 8
    const int which = blockIdx.y;             // 0=Q 1=K 2=V
    const int lt = blockIdx.z;                // 32 tiles of 64 l
    const int tid = threadIdx.x;
    const int wv = tid >> 6;                  // 4 waves
    const int lane = tid & 63;
    const int ql = lane & 31;
    const int hi = lane >> 5;
    const int l = lt * 64 + (wv & 1) * 32 + ql;   // this lane's output row
    const int hbase = (wv >> 1) * 2;              // head pair

    const float* W = (which == 0 ? Wq : (which == 1 ? Wk : Wv));
    const float* xcol = x + (size_t)b * DM * LSEQ + l;   // x[b][d][l]

    f32x16 acc0, acc1;
    #pragma unroll
    for (int r = 0; r < 16; ++r) { acc0[r] = 0.f; acc1[r] = 0.f; }

    #pragma unroll
    for (int d0 = 0; d0 < DM; d0 += 16) {
        const int dbase = d0 + 8 * hi;
        float xv[8];
        #pragma unroll
        for (int i = 0; i < 8; ++i) xv[i] = xcol[(size_t)(dbase + i) * LSEQ];
        uint4 xp = make_uint4(pack_bf2(xv[0], xv[1]), pack_bf2(xv[2], xv[3]),
                              pack_bf2(xv[4], xv[5]), pack_bf2(xv[6], xv[7]));
        const bf16x8 xf = as_bf16x8(xp);
        const float* wr0 = W + ((size_t)(hbase + 0) * DM + dbase) * DK + ql;
        const float* wr1 = W + ((size_t)(hbase + 1) * DM + dbase) * DK + ql;
        float w0[8], w1[8];
        #pragma unroll
        for (int i = 0; i < 8; ++i) { w0[i] = wr0[i * DK]; w1[i] = wr1[i * DK]; }
        uint4 wp0 = make_uint4(pack_bf2(w0[0], w0[1]), pack_bf2(w0[2], w0[3]),
                               pack_bf2(w0[4], w0[5]), pack_bf2(w0[6], w0[7]));
        uint4 wp1 = make_uint4(pack_bf2(w1[0], w1[1]), pack_bf2(w1[2], w1[3]),
                               pack_bf2(w1[4], w1[5]), pack_bf2(w1[6], w1[7]));
        acc0 = __builtin_amdgcn_mfma_f32_32x32x16_bf16(as_bf16x8(wp0), xf, acc0, 0, 0, 0);
        acc1 = __builtin_amdgcn_mfma_f32_32x32x16_bf16(as_bf16x8(wp1), xf, acc1, 0, 0, 0);
    }

    bool store = true;
    int slot = l;
    if (which != 0) {
        if (mask[(size_t)b * LSEQ + l] == 0.0f) slot = cpos[(size_t)b * LSEQ + l];
        else store = false;
    }
    if (store) {
        const float fold = (which == 0) ? SL : 1.0f;
        unsigned short* base0 = (which == 0 ? Qb : (which == 1 ? Kb : Vcb));
        #pragma unroll
        for (int hh = 0; hh < 2; ++hh) {
            const f32x16& A = hh ? acc1 : acc0;
            const int bh = b * NH + hbase + hh;
            unsigned short* rowp = base0 + ((size_t)bh * LSEQ + slot) * DK;
            unsigned dw[8];
            #pragma unroll
            for (int j = 0; j < 8; ++j) dw[j] = pack_bf2(A[2*j] * fold, A[2*j+1] * fold);
            *reinterpret_cast<uint2*>(rowp + 4*hi)      = make_uint2(dw[0], dw[1]);
            *reinterpret_cast<uint2*>(rowp + 8 + 4*hi)  = make_uint2(dw[2], dw[3]);
            *reinterpret_cast<uint2*>(rowp + 16 + 4*hi) = make_uint2(dw[4], dw[5]);
            *reinterpret_cast<uint2*>(rowp + 24 + 4*hi) = make_uint2(dw[6], dw[7]);
        }
    }
}

// ---------- kernel 1b: transpose Vcb[slot][32] -> Vt[d][slot] (bf16) ----------
__global__ __launch_bounds__(256) void vtrans_kernel(const unsigned short* __restrict__ Vcb,
                                                     unsigned short* __restrict__ Vt)
{
    const int bh = blockIdx.y;
    const int s0 = blockIdx.x * 256;
    __shared__ unsigned lds[256][17];
    const int t = threadIdx.x;
    const uint4* src = reinterpret_cast<const uint4*>(Vcb + ((size_t)bh * LSEQ + s0 + t) * DK);
    uint4 r0 = src[0], r1 = src[1], r2 = src[2], r3 = src[3];
    unsigned* lr = lds[t];
    lr[0]=r0.x;  lr[1]=r0.y;  lr[2]=r0.z;  lr[3]=r0.w;
    lr[4]=r1.x;  lr[5]=r1.y;  lr[6]=r1.z;  lr[7]=r1.w;
    lr[8]=r2.x;  lr[9]=r2.y;  lr[10]=r2.z; lr[11]=r2.w;
    lr[12]=r3.x; lr[13]=r3.y; lr[14]=r3.z; lr[15]=r3.w;
    __syncthreads();
    const int d = t & 31;
    const int c = (t >> 5) * 32;
    const int dw = d >> 1;
    const int dh = (d & 1) * 16;
    unsigned ow[16];
    #pragma unroll
    for (int i = 0; i < 16; ++i) {
        unsigned lo = (lds[c + 2*i][dw] >> dh) & 0xffffu;
        unsigned hv = (lds[c + 2*i + 1][dw] >> dh) & 0xffffu;
        ow[i] = lo | (hv << 16);
    }
    uint4* dstp = reinterpret_cast<uint4*>(Vt + ((size_t)bh * DK + d) * LSEQ + s0 + c);
    dstp[0] = make_uint4(ow[0],  ow[1],  ow[2],  ow[3]);
    dstp[1] = make_uint4(ow[4],  ow[5],  ow[6],  ow[7]);
    dstp[2] = make_uint4(ow[8],  ow[9],  ow[10], ow[11]);
    dstp[3] = make_uint4(ow[12], ow[13], ow[14], ow[15]);
}

// ---------- kernel 2: MFMA flash attention, 4-way key split ----------
// Register double-buffered K/V tile pipeline; no spills (VGPR cap 128).
__global__ __launch_bounds__(256, 4) void attn_kernel(
    const unsigned short* __restrict__ Qb, const unsigned short* __restrict__ Kb,
    const unsigned short* __restrict__ Vt, const float* __restrict__ mask,
    const int* __restrict__ cnt, unsigned short* __restrict__ Hd)
{
    const int bh = blockIdx.y;
    const int b = bh >> 2;
    const int h = bh & 3;
    const int lane = threadIdx.x & 63;
    const int kw = threadIdx.x >> 6;              // key-quarter owner (0..3)
    const int ql = lane & 31;
    const int hi = lane >> 5;
    const int q0 = blockIdx.x * 32;
    const int n = cnt[b];

    const uint4* Qp = reinterpret_cast<const uint4*>(Qb + ((size_t)bh * LSEQ + q0 + ql) * DK);
    const bf16x8 qf0 = as_bf16x8(Qp[hi]);         // Q[q=ql][d=8*hi+i] (pre-scaled)
    const bf16x8 qf1 = as_bf16x8(Qp[2 + hi]);     // d = 16+8*hi+i

    const unsigned short* Kbase = Kb + (size_t)bh * LSEQ * DK;
    const unsigned short* Vbase = Vt + ((size_t)bh * DK + ql) * LSEQ;

    f32x16 acc;
    #pragma unroll
    for (int r = 0; r < 16; ++r) acc[r] = 0.f;
    f32x16 zero;
    #pragma unroll
    for (int r = 0; r < 16; ++r) zero[r] = 0.f;
    float la0 = 0.f, la1 = 0.f;

    auto ldk0 = [&](int k) { return reinterpret_cast<const uint4*>(Kbase + (size_t)(k + ql) * DK)[hi]; };
    auto ldk1 = [&](int k) { return reinterpret_cast<const uint4*>(Kbase + (size_t)(k + ql) * DK)[2 + hi]; };
    auto ldv0 = [&](int k) { return reinterpret_cast<const uint4*>(Vbase + k)[hi]; };
    auto ldv1 = [&](int k) { return reinterpret_cast<const uint4*>(Vbase + k)[2 + hi]; };

    auto compute = [&](uint4 kv0, uint4 kv1, uint4 vv0, uint4 vv1, int k0, bool pred) {
        f32x16 s = __builtin_amdgcn_mfma_f32_32x32x16_bf16(as_bf16x8(kv0), qf0, zero, 0, 0, 0);
        s = __builtin_amdgcn_mfma_f32_32x32x16_bf16(as_bf16x8(kv1), qf1, s, 0, 0, 0);
        unsigned w[8], sw[8];
        #pragma unroll
        for (int j = 0; j < 8; ++j) {
            float e0 = exp2f(s[2*j]);             // key = k0+(r&3)+8*(r>>2)+4*hi
            float e1 = exp2f(s[2*j+1]);
            if (pred) {
                const int r0 = 2*j, r1 = 2*j + 1;
                if (k0 + (r0 & 3) + 8*(r0 >> 2) + 4*hi >= n) e0 = 0.f;
                if (k0 + (r1 & 3) + 8*(r1 >> 2) + 4*hi >= n) e1 = 0.f;
            }
            la0 += e0;                             // two independent chains
            la1 += e1;
            w[j] = pack_bf2(e0, e1);
        }
        #pragma unroll
        for (int j = 0; j < 8; ++j) sw[j] = __shfl_xor(w[j], 32);
        uint4 b0 = hi ? make_uint4(sw[2], sw[3], w[2], w[3])
                      : make_uint4(w[0], w[1], sw[0], sw[1]);
        uint4 b1 = hi ? make_uint4(sw[6], sw[7], w[6], w[7])
                      : make_uint4(w[4], w[5], sw[4], sw[5]);
        acc = __builtin_amdgcn_mfma_f32_32x32x16_bf16(as_bf16x8(vv0), as_bf16x8(b0), acc, 0, 0, 0);
        acc = __builtin_amdgcn_mfma_f32_32x32x16_bf16(as_bf16x8(vv1), as_bf16x8(b1), acc, 0, 0, 0);
    };

    const int nfull = n & ~31;
    int k = kw * 32;
    if (k < nfull) {
        uint4 ka0 = ldk0(k), ka1 = ldk1(k), va0 = ldv0(k), va1 = ldv1(k);
        for (; k + 128 < nfull; k += 128) {
            // prefetch next tile (in-range: k+128 < nfull) while computing current
            uint4 kb0 = ldk0(k + 128), kb1 = ldk1(k + 128);
            uint4 vb0 = ldv0(k + 128), vb1 = ldv1(k + 128);
            compute(ka0, ka1, va0, va1, k, false);
            ka0 = kb0; ka1 = kb1; va0 = vb0; va1 = vb1;
        }
        compute(ka0, ka1, va0, va1, k, false);
    }
    if (n & 31) {
        if (((nfull >> 5) & 3) == kw) {
            uint4 ka0 = ldk0(nfull), ka1 = ldk1(nfull);
            uint4 va0 = ldv0(nfull), va1 = ldv1(nfull);
            compute(ka0, ka1, va0, va1, nfull, true);
        }
    }

    // merge 4 wave-partials (pure sums) via LDS
    float lacc = la0 + la1;
    __shared__ float red[3][64][17];
    if (kw > 0) {
        #pragma unroll
        for (int r = 0; r < 16; ++r) red[kw - 1][lane][r] = acc[r];
        red[kw - 1][lane][16] = lacc;
    }
    __syncthreads();
    if (kw == 0) {
        #pragma unroll
        for (int c = 0; c < 3; ++c) {
            #pragma unroll
            for (int r = 0; r < 16; ++r) acc[r] += red[c][lane][r];
            lacc += red[c][lane][16];
        }
        const float lf = lacc + __shfl_xor(lacc, 32);
        const float mq = mask[(size_t)b * LSEQ + q0 + ql];
        const float wgt = (lf > 0.f) ? (mq / lf) : 0.f;
        unsigned short* orow = Hd + ((size_t)b * LSEQ + q0 + ql) * DM + h * DK + 4 * hi;
        #pragma unroll
        for (int g = 0; g < 4; ++g) {            // d = 8g + 4hi + (0..3)
            uint2 p = make_uint2(pack_bf2(acc[4*g+0]*wgt, acc[4*g+1]*wgt),
                                 pack_bf2(acc[4*g+2]*wgt, acc[4*g+3]*wgt));
            *reinterpret_cast<uint2*>(orow + 8*g) = p;
        }
    }
}

// ---------- kernel 3: output projection via MFMA + transposed store ----------
__global__ __launch_bounds__(256) void proj_mfma_kernel(const unsigned short* __restrict__ Hd,
    const float* __restrict__ Wo, float* __restrict__ out)
{
    const int blk = blockIdx.x;                   // 512 = 8 b x 64 l-tiles
    const int b = blk >> 6;
    const int l0 = (blk & 63) * 32;
    const int tid = threadIdx.x;
    const int jt = tid >> 6;                      // j-tile per wave
    const int lane = tid & 63;
    const int ql = lane & 31;
    const int hi = lane >> 5;

    const unsigned short* hrow = Hd + ((size_t)b * LSEQ + l0 + ql) * DM;

    f32x16 acc;
    #pragma unroll
    for (int r = 0; r < 16; ++r) acc[r] = 0.f;

    #pragma unroll
    for (int ks = 0; ks < 8; ++ks) {
        const int k0 = ks * 16 + 8 * hi;
        uint4 bp = *reinterpret_cast<const uint4*>(hrow + k0);      // Hd[l][k0..k0+7]
        const float* wcol = Wo + (size_t)k0 * DM + jt * 32 + ql;    // Wo[k][j]
        float w[8];
        #pragma unroll
        for (int i = 0; i < 8; ++i) w[i] = wcol[(size_t)i * DM];
        uint4 ap = make_uint4(pack_bf2(w[0], w[1]), pack_bf2(w[2], w[3]),
                              pack_bf2(w[4], w[5]), pack_bf2(w[6], w[7]));
        acc = __builtin_amdgcn_mfma_f32_32x32x16_bf16(as_bf16x8(ap), as_bf16x8(bp), acc, 0, 0, 0);
    }

    float* obase = out + (size_t)b * DM * LSEQ + l0 + ql;
    #pragma unroll
    for (int r = 0; r < 16; ++r) {
        const int j = jt * 32 + (r & 3) + 8 * (r >> 2) + 4 * hi;
        obase[(size_t)j * LSEQ] = acc[r];         // coalesced across ql
    }
}

extern "C" void kernel_launch(void* const* d_in, const int* in_sizes, int n_in,
                              void* d_out, int out_size, void* d_ws, size_t ws_size,
                              hipStream_t stream)
{
    const float* x    = (const float*)d_in[0];
    const float* mask = (const float*)d_in[1];
    const float* Wq   = (const float*)d_in[2];
    const float* Wk   = (const float*)d_in[3];
    const float* Wv   = (const float*)d_in[4];
    const float* Wo   = (const float*)d_in[5];
    float* out = (float*)d_out;

    char* wsb = (char*)d_ws;
    const size_t NBF = (size_t)BATCH * NH * LSEQ * DK;      // 2,097,152 elems
    unsigned short* Qb  = (unsigned short*)wsb;             // 4MB
    unsigned short* Kb  = Qb + NBF;                         // 4MB
    unsigned short* Vcb = Kb + NBF;                         // 4MB
    unsigned short* Vt  = Vcb + NBF;                        // 4MB
    unsigned short* Hd  = Vt + NBF;                         // 4MB bf16 (B,L,128)
    int* cpos = (int*)(wsb + 24ull * 1024 * 1024);
    int* cnt  = cpos + (size_t)BATCH * LSEQ;

    scan_kernel<<<dim3(BATCH), dim3(256), 0, stream>>>(mask, cpos, cnt);
    qkv_mfma_kernel<<<dim3(BATCH, 3, LSEQ / 64), dim3(256), 0, stream>>>(
        x, Wq, Wk, Wv, mask, cpos, Qb, Kb, Vcb);
    vtrans_kernel<<<dim3(LSEQ / 256, BATCH * NH), dim3(256), 0, stream>>>(Vcb, Vt);
    attn_kernel<<<dim3(LSEQ / 32, BATCH * NH), dim3(256), 0, stream>>>(
        Qb, Kb, Vt, mask, cnt, Hd);
    proj_mfma_kernel<<<dim3(BATCH * LSEQ / 32), dim3(256), 0, stream>>>(Hd, Wo, out);
}

// Round 7
// 56.705 us; speedup vs baseline: 1.5869x; 1.0522x over previous
//
#include <hip/hip_runtime.h>
#include <hip/hip_bf16.h>
#include <math.h>

#define BATCH 8
#define LSEQ 2048
#define DM 128
#define NH 4
#define DK 32

constexpr float SCALE = 0.17677669529663687f;   // 1/sqrt(32)
constexpr float LOG2E = 1.4426950408889634f;
constexpr float SL = SCALE * LOG2E;             // folded into Q at qkv store

typedef __attribute__((ext_vector_type(8))) __bf16 bf16x8;
typedef __attribute__((ext_vector_type(16))) float f32x16;
typedef __attribute__((ext_vector_type(2))) unsigned uint2v;

__device__ __forceinline__ bf16x8 as_bf16x8(uint4 u) {
    union { uint4 a; bf16x8 b; } c; c.a = u; return c.b;
}
__device__ __forceinline__ unsigned pack_bf2(float lo, float hi) {
    __hip_bfloat162 h = __float22bfloat162_rn(make_float2(lo, hi));
    union { __hip_bfloat162 a; unsigned b; } c; c.a = h; return c.b;
}

// ---------- kernel 0: per-batch exclusive scan of unmasked keys ----------
__global__ __launch_bounds__(256) void scan_kernel(const float* __restrict__ mask,
                                                   int* __restrict__ cpos,
                                                   int* __restrict__ cnt)
{
    const int b = blockIdx.x;
    const int tid = threadIdx.x;
    __shared__ int ps[256];
    const float* mb = mask + (size_t)b * LSEQ;
    const int base = tid * 8;
    int loc[8];
    int sum = 0;
    #pragma unroll
    for (int i = 0; i < 8; ++i) {
        int u = (mb[base + i] == 0.0f) ? 1 : 0;
        loc[i] = sum;
        sum += u;
    }
    ps[tid] = sum;
    __syncthreads();
    for (int off = 1; off < 256; off <<= 1) {
        int v = (tid >= off) ? ps[tid - off] : 0;
        __syncthreads();
        ps[tid] += v;
        __syncthreads();
    }
    const int prev = (tid > 0) ? ps[tid - 1] : 0;
    #pragma unroll
    for (int i = 0; i < 8; ++i)
        cpos[(size_t)b * LSEQ + base + i] = prev + loc[i];
    if (tid == 255) cnt[b] = ps[255];
}

// ---------- kernel 1: QKV projection via MFMA ----------
// Q is pre-scaled by SCALE*LOG2E so attn can exp2 scores directly.
__global__ __launch_bounds__(256) void qkv_mfma_kernel(const float* __restrict__ x,
    const float* __restrict__ Wq, const float* __restrict__ Wk, const float* __restrict__ Wv,
    const float* __restrict__ mask, const int* __restrict__ cpos,
    unsigned short* __restrict__ Qb, unsigned short* __restrict__ Kb,
    unsigned short* __restrict__ Vcb)
{
    const int b = blockIdx.x;                 // 8
    const int which = blockIdx.y;             // 0=Q 1=K 2=V
    const int lt = blockIdx.z;                // 32 tiles of 64 l
    const int tid = threadIdx.x;
    const int wv = tid >> 6;                  // 4 waves
    const int lane = tid & 63;
    const int ql = lane & 31;
    const int hi = lane >> 5;
    const int l = lt * 64 + (wv & 1) * 32 + ql;   // this lane's output row
    const int hbase = (wv >> 1) * 2;              // head pair

    const float* W = (which == 0 ? Wq : (which == 1 ? Wk : Wv));
    const float* xcol = x + (size_t)b * DM * LSEQ + l;   // x[b][d][l]

    f32x16 acc0, acc1;
    #pragma unroll
    for (int r = 0; r < 16; ++r) { acc0[r] = 0.f; acc1[r] = 0.f; }

    #pragma unroll
    for (int d0 = 0; d0 < DM; d0 += 16) {
        const int dbase = d0 + 8 * hi;
        float xv[8];
        #pragma unroll
        for (int i = 0; i < 8; ++i) xv[i] = xcol[(size_t)(dbase + i) * LSEQ];
        uint4 xp = make_uint4(pack_bf2(xv[0], xv[1]), pack_bf2(xv[2], xv[3]),
                              pack_bf2(xv[4], xv[5]), pack_bf2(xv[6], xv[7]));
        const bf16x8 xf = as_bf16x8(xp);
        const float* wr0 = W + ((size_t)(hbase + 0) * DM + dbase) * DK + ql;
        const float* wr1 = W + ((size_t)(hbase + 1) * DM + dbase) * DK + ql;
        float w0[8], w1[8];
        #pragma unroll
        for (int i = 0; i < 8; ++i) { w0[i] = wr0[i * DK]; w1[i] = wr1[i * DK]; }
        uint4 wp0 = make_uint4(pack_bf2(w0[0], w0[1]), pack_bf2(w0[2], w0[3]),
                               pack_bf2(w0[4], w0[5]), pack_bf2(w0[6], w0[7]));
        uint4 wp1 = make_uint4(pack_bf2(w1[0], w1[1]), pack_bf2(w1[2], w1[3]),
                               pack_bf2(w1[4], w1[5]), pack_bf2(w1[6], w1[7]));
        acc0 = __builtin_amdgcn_mfma_f32_32x32x16_bf16(as_bf16x8(wp0), xf, acc0, 0, 0, 0);
        acc1 = __builtin_amdgcn_mfma_f32_32x32x16_bf16(as_bf16x8(wp1), xf, acc1, 0, 0, 0);
    }

    bool store = true;
    int slot = l;
    if (which != 0) {
        if (mask[(size_t)b * LSEQ + l] == 0.0f) slot = cpos[(size_t)b * LSEQ + l];
        else store = false;
    }
    if (store) {
        const float fold = (which == 0) ? SL : 1.0f;
        unsigned short* base0 = (which == 0 ? Qb : (which == 1 ? Kb : Vcb));
        #pragma unroll
        for (int hh = 0; hh < 2; ++hh) {
            const f32x16& A = hh ? acc1 : acc0;
            const int bh = b * NH + hbase + hh;
            unsigned short* rowp = base0 + ((size_t)bh * LSEQ + slot) * DK;
            unsigned dw[8];
            #pragma unroll
            for (int j = 0; j < 8; ++j) dw[j] = pack_bf2(A[2*j] * fold, A[2*j+1] * fold);
            *reinterpret_cast<uint2*>(rowp + 4*hi)      = make_uint2(dw[0], dw[1]);
            *reinterpret_cast<uint2*>(rowp + 8 + 4*hi)  = make_uint2(dw[2], dw[3]);
            *reinterpret_cast<uint2*>(rowp + 16 + 4*hi) = make_uint2(dw[4], dw[5]);
            *reinterpret_cast<uint2*>(rowp + 24 + 4*hi) = make_uint2(dw[6], dw[7]);
        }
    }
}

// ---------- kernel 1b: Vcb[slot][32] -> V4 MFMA-A-fragment layout ----------
// V4[bh][kt][j][lane][i] = V^T[d=lane&31][key = kt*32 + 16j + 8*(lane>>5) + i]
// so attn's V load is a fully coalesced 1KB wave read: Vp[lane], Vp[64+lane].
__global__ __launch_bounds__(256) void vfrag_kernel(const unsigned short* __restrict__ Vcb,
                                                    unsigned short* __restrict__ V4)
{
    const int bh = blockIdx.y;
    const int s0 = blockIdx.x * 256;            // 256 keys per block (8 k-tiles)
    __shared__ unsigned short lsd[256][34];     // stride 34 u16 -> conflict-light
    const int t = threadIdx.x;
    const uint4* src = reinterpret_cast<const uint4*>(Vcb + ((size_t)bh * LSEQ + s0 + t) * DK);
    uint4 r0 = src[0], r1 = src[1], r2 = src[2], r3 = src[3];
    unsigned* lw = reinterpret_cast<unsigned*>(&lsd[t][0]);   // byte offset t*68, 4B-aligned
    lw[0]=r0.x;  lw[1]=r0.y;  lw[2]=r0.z;  lw[3]=r0.w;
    lw[4]=r1.x;  lw[5]=r1.y;  lw[6]=r1.z;  lw[7]=r1.w;
    lw[8]=r2.x;  lw[9]=r2.y;  lw[10]=r2.z; lw[11]=r2.w;
    lw[12]=r3.x; lw[13]=r3.y; lw[14]=r3.z; lw[15]=r3.w;
    __syncthreads();
    uint4* dst = reinterpret_cast<uint4*>(V4 + (size_t)bh * LSEQ * DK + (size_t)s0 * DK);
    #pragma unroll
    for (int p = 0; p < 4; ++p) {
        const int u = t + 256 * p;              // uint4 index within this 8-kt chunk
        const int ktl = u >> 7;
        const int j = (u >> 6) & 1;
        const int lane = u & 63;
        const int d = lane & 31;
        const int h2 = lane >> 5;
        const int krow = ktl * 32 + 16 * j + 8 * h2;
        unsigned ow[4];
        #pragma unroll
        for (int m = 0; m < 4; ++m) {
            unsigned lo  = lsd[krow + 2*m][d];
            unsigned hi2 = lsd[krow + 2*m + 1][d];
            ow[m] = lo | (hi2 << 16);
        }
        dst[u] = make_uint4(ow[0], ow[1], ow[2], ow[3]);
    }
}

// ---------- kernel 2: MFMA flash attention, 4-way key split ----------
// Register double-buffered K/V pipeline; coalesced V4 frags; permlane32_swap
// replaces shfl_xor for the P^T half-exchange (VALU-only, no LDS latency).
__global__ __launch_bounds__(256, 4) void attn_kernel(
    const unsigned short* __restrict__ Qb, const unsigned short* __restrict__ Kb,
    const unsigned short* __restrict__ V4, const float* __restrict__ mask,
    const int* __restrict__ cnt, unsigned short* __restrict__ Hd)
{
    const int bh = blockIdx.y;
    const int b = bh >> 2;
    const int h = bh & 3;
    const int lane = threadIdx.x & 63;
    const int kw = threadIdx.x >> 6;              // key-quarter owner (0..3)
    const int ql = lane & 31;
    const int hi = lane >> 5;
    const int q0 = blockIdx.x * 32;
    const int n = cnt[b];

    const uint4* Qp = reinterpret_cast<const uint4*>(Qb + ((size_t)bh * LSEQ + q0 + ql) * DK);
    const bf16x8 qf0 = as_bf16x8(Qp[hi]);         // Q[q=ql][d=8*hi+i] (pre-scaled)
    const bf16x8 qf1 = as_bf16x8(Qp[2 + hi]);     // d = 16+8*hi+i

    const unsigned short* Kbase = Kb + (size_t)bh * LSEQ * DK;
    const unsigned short* Vb4   = V4 + (size_t)bh * LSEQ * DK;

    f32x16 acc;
    #pragma unroll
    for (int r = 0; r < 16; ++r) acc[r] = 0.f;
    f32x16 zero;
    #pragma unroll
    for (int r = 0; r < 16; ++r) zero[r] = 0.f;
    float la0 = 0.f, la1 = 0.f;

    auto ldk0 = [&](int k) { return reinterpret_cast<const uint4*>(Kbase + (size_t)(k + ql) * DK)[hi]; };
    auto ldk1 = [&](int k) { return reinterpret_cast<const uint4*>(Kbase + (size_t)(k + ql) * DK)[2 + hi]; };
    auto ldv0 = [&](int k) { return reinterpret_cast<const uint4*>(Vb4 + (size_t)(k >> 5) * 1024)[lane]; };
    auto ldv1 = [&](int k) { return reinterpret_cast<const uint4*>(Vb4 + (size_t)(k >> 5) * 1024)[64 + lane]; };

    auto compute = [&](uint4 kv0, uint4 kv1, uint4 vv0, uint4 vv1, int k0, bool pred) {
        f32x16 s = __builtin_amdgcn_mfma_f32_32x32x16_bf16(as_bf16x8(kv0), qf0, zero, 0, 0, 0);
        s = __builtin_amdgcn_mfma_f32_32x32x16_bf16(as_bf16x8(kv1), qf1, s, 0, 0, 0);
        unsigned w[8];
        #pragma unroll
        for (int j = 0; j < 8; ++j) {
            float e0 = exp2f(s[2*j]);             // key = k0+(r&3)+8*(r>>2)+4*hi
            float e1 = exp2f(s[2*j+1]);
            if (pred) {
                const int r0 = 2*j, r1 = 2*j + 1;
                if (k0 + (r0 & 3) + 8*(r0 >> 2) + 4*hi >= n) e0 = 0.f;
                if (k0 + (r1 & 3) + 8*(r1 >> 2) + 4*hi >= n) e1 = 0.f;
            }
            la0 += e0;                             // two independent chains
            la1 += e1;
            w[j] = pack_bf2(e0, e1);
        }
        // half-exchange via permlane32_swap: one swap fills two output words.
        // swap(a,b) -> { {a_lo, b_lo}, {a_hi, b_hi} } across the lane<32/>=32 split.
        uint2v p0 = __builtin_amdgcn_permlane32_swap(w[0], w[2], false, false);
        uint2v p1 = __builtin_amdgcn_permlane32_swap(w[1], w[3], false, false);
        uint2v p2 = __builtin_amdgcn_permlane32_swap(w[4], w[6], false, false);
        uint2v p3 = __builtin_amdgcn_permlane32_swap(w[5], w[7], false, false);
        uint4 b0 = make_uint4(p0[0], p1[0], p0[1], p1[1]);
        uint4 b1 = make_uint4(p2[0], p3[0], p2[1], p3[1]);
        acc = __builtin_amdgcn_mfma_f32_32x32x16_bf16(as_bf16x8(vv0), as_bf16x8(b0), acc, 0, 0, 0);
        acc = __builtin_amdgcn_mfma_f32_32x32x16_bf16(as_bf16x8(vv1), as_bf16x8(b1), acc, 0, 0, 0);
    };

    const int nfull = n & ~31;
    int k = kw * 32;
    if (k < nfull) {
        uint4 ka0 = ldk0(k), ka1 = ldk1(k), va0 = ldv0(k), va1 = ldv1(k);
        for (; k + 128 < nfull; k += 128) {
            uint4 kb0 = ldk0(k + 128), kb1 = ldk1(k + 128);
            uint4 vb0 = ldv0(k + 128), vb1 = ldv1(k + 128);
            compute(ka0, ka1, va0, va1, k, false);
            ka0 = kb0; ka1 = kb1; va0 = vb0; va1 = vb1;
        }
        compute(ka0, ka1, va0, va1, k, false);
    }
    if (n & 31) {
        if (((nfull >> 5) & 3) == kw) {
            uint4 ka0 = ldk0(nfull), ka1 = ldk1(nfull);
            uint4 va0 = ldv0(nfull), va1 = ldv1(nfull);
            compute(ka0, ka1, va0, va1, nfull, true);
        }
    }

    // merge 4 wave-partials (pure sums) via LDS
    float lacc = la0 + la1;
    __shared__ float red[3][64][17];
    if (kw > 0) {
        #pragma unroll
        for (int r = 0; r < 16; ++r) red[kw - 1][lane][r] = acc[r];
        red[kw - 1][lane][16] = lacc;
    }
    __syncthreads();
    if (kw == 0) {
        #pragma unroll
        for (int c = 0; c < 3; ++c) {
            #pragma unroll
            for (int r = 0; r < 16; ++r) acc[r] += red[c][lane][r];
            lacc += red[c][lane][16];
        }
        const float lf = lacc + __shfl_xor(lacc, 32);
        const float mq = mask[(size_t)b * LSEQ + q0 + ql];
        const float wgt = (lf > 0.f) ? (mq / lf) : 0.f;
        unsigned short* orow = Hd + ((size_t)b * LSEQ + q0 + ql) * DM + h * DK + 4 * hi;
        #pragma unroll
        for (int g = 0; g < 4; ++g) {            // d = 8g + 4hi + (0..3)
            uint2 p = make_uint2(pack_bf2(acc[4*g+0]*wgt, acc[4*g+1]*wgt),
                                 pack_bf2(acc[4*g+2]*wgt, acc[4*g+3]*wgt));
            *reinterpret_cast<uint2*>(orow + 8*g) = p;
        }
    }
}

// ---------- kernel 3: output projection via MFMA + transposed store ----------
__global__ __launch_bounds__(256) void proj_mfma_kernel(const unsigned short* __restrict__ Hd,
    const float* __restrict__ Wo, float* __restrict__ out)
{
    const int blk = blockIdx.x;                   // 512 = 8 b x 64 l-tiles
    const int b = blk >> 6;
    const int l0 = (blk & 63) * 32;
    const int tid = threadIdx.x;
    const int jt = tid >> 6;                      // j-tile per wave
    const int lane = tid & 63;
    const int ql = lane & 31;
    const int hi = lane >> 5;

    const unsigned short* hrow = Hd + ((size_t)b * LSEQ + l0 + ql) * DM;

    f32x16 acc;
    #pragma unroll
    for (int r = 0; r < 16; ++r) acc[r] = 0.f;

    #pragma unroll
    for (int ks = 0; ks < 8; ++ks) {
        const int k0 = ks * 16 + 8 * hi;
        uint4 bp = *reinterpret_cast<const uint4*>(hrow + k0);      // Hd[l][k0..k0+7]
        const float* wcol = Wo + (size_t)k0 * DM + jt * 32 + ql;    // Wo[k][j]
        float w[8];
        #pragma unroll
        for (int i = 0; i < 8; ++i) w[i] = wcol[(size_t)i * DM];
        uint4 ap = make_uint4(pack_bf2(w[0], w[1]), pack_bf2(w[2], w[3]),
                              pack_bf2(w[4], w[5]), pack_bf2(w[6], w[7]));
        acc = __builtin_amdgcn_mfma_f32_32x32x16_bf16(as_bf16x8(ap), as_bf16x8(bp), acc, 0, 0, 0);
    }

    float* obase = out + (size_t)b * DM * LSEQ + l0 + ql;
    #pragma unroll
    for (int r = 0; r < 16; ++r) {
        const int j = jt * 32 + (r & 3) + 8 * (r >> 2) + 4 * hi;
        obase[(size_t)j * LSEQ] = acc[r];         // coalesced across ql
    }
}

extern "C" void kernel_launch(void* const* d_in, const int* in_sizes, int n_in,
                              void* d_out, int out_size, void* d_ws, size_t ws_size,
                              hipStream_t stream)
{
    const float* x    = (const float*)d_in[0];
    const float* mask = (const float*)d_in[1];
    const float* Wq   = (const float*)d_in[2];
    const float* Wk   = (const float*)d_in[3];
    const float* Wv   = (const float*)d_in[4];
    const float* Wo   = (const float*)d_in[5];
    float* out = (float*)d_out;

    char* wsb = (char*)d_ws;
    const size_t NBF = (size_t)BATCH * NH * LSEQ * DK;      // 2,097,152 elems
    unsigned short* Qb  = (unsigned short*)wsb;             // 4MB
    unsigned short* Kb  = Qb + NBF;                         // 4MB
    unsigned short* Vcb = Kb + NBF;                         // 4MB
    unsigned short* V4  = Vcb + NBF;                        // 4MB frag-layout V
    unsigned short* Hd  = V4 + NBF;                         // 4MB bf16 (B,L,128)
    int* cpos = (int*)(wsb + 24ull * 1024 * 1024);
    int* cnt  = cpos + (size_t)BATCH * LSEQ;

    scan_kernel<<<dim3(BATCH), dim3(256), 0, stream>>>(mask, cpos, cnt);
    qkv_mfma_kernel<<<dim3(BATCH, 3, LSEQ / 64), dim3(256), 0, stream>>>(
        x, Wq, Wk, Wv, mask, cpos, Qb, Kb, Vcb);
    vfrag_kernel<<<dim3(LSEQ / 256, BATCH * NH), dim3(256), 0, stream>>>(Vcb, V4);
    attn_kernel<<<dim3(LSEQ / 32, BATCH * NH), dim3(256), 0, stream>>>(
        Qb, Kb, V4, mask, cnt, Hd);
    proj_mfma_kernel<<<dim3(BATCH * LSEQ / 32), dim3(256), 0, stream>>>(Hd, Wo, out);
}